// Round 1
// baseline (743.328 us; speedup 1.0000x reference)
//
#include <hip/hip_runtime.h>
#include <hip/hip_bf16.h>

typedef unsigned int uint;
typedef unsigned short ushort;
typedef float v2f __attribute__((ext_vector_type(2)));

#define NATOMS 20000
#define NEDGES 640000
#define FD 128
#define F3 384
#define NR 20
#define MAPB 16     // atoms per block, MLP
#define GAPB 2      // atoms per block, gather

__device__ __forceinline__ uint f2bfu(float f) {   // f32 -> bf16 bits, RNE
  const uint u = __float_as_uint(f);
  return (u + 0x7FFFu + ((u >> 16) & 1u)) >> 16;
}
__device__ __forceinline__ float bflo(uint u) { return __uint_as_float(u << 16); }
__device__ __forceinline__ float bfhi(uint u) { return __uint_as_float(u & 0xFFFF0000u); }

// ---------------------------------------------------------------------------
// CSR build: histogram -> exclusive scan (writes off AND cursor).
// ---------------------------------------------------------------------------
__global__ __launch_bounds__(256) void hist_kernel(const int* __restrict__ eidx,
                                                   int* __restrict__ cnt) {
  const int e = blockIdx.x * 256 + threadIdx.x;
  if (e < NEDGES) atomicAdd(&cnt[eidx[e]], 1);
}

__global__ __launch_bounds__(512) void scan_kernel(const int* __restrict__ cnt,
                                                   int* __restrict__ off,
                                                   int* __restrict__ cursor) {
  __shared__ int part[512];
  const int t = threadIdx.x;
  const int CH = (NATOMS + 511) / 512;
  const int base = t * CH;
  int s = 0;
  for (int k = 0; k < CH; ++k) {
    const int idx = base + k;
    if (idx < NATOMS) s += cnt[idx];
  }
  part[t] = s;
  __syncthreads();
  if (t == 0) {
    int run = 0;
    for (int i = 0; i < 512; ++i) { const int tmp = part[i]; part[i] = run; run += tmp; }
    off[NATOMS] = run;
  }
  __syncthreads();
  int run = part[t];
  for (int k = 0; k < CH; ++k) {
    const int idx = base + k;
    if (idx < NATOMS) { off[idx] = run; cursor[idx] = run; run += cnt[idx]; }
  }
}

// ---------------------------------------------------------------------------
// Prep: 32B record at destination-sorted position.
// rec: [0] v0=sin(th)*env/d  [1] 2cos(th)  [2] env  [3..5] dir  [6] j  [7] pad
// ---------------------------------------------------------------------------
__global__ __launch_bounds__(256) void prep_kernel(
    const int* __restrict__ eidx, const float* __restrict__ ew,
    int* __restrict__ cursor, uint4* __restrict__ basisS)
{
  const int e = blockIdx.x * 256 + threadIdx.x;
  if (e >= NEDGES) return;
  const int i = eidx[e];
  const int j = eidx[NEDGES + e];
  const int pos = atomicAdd(&cursor[i], 1);

  const float w0 = ew[(size_t)e * 3 + 0];
  const float w1 = ew[(size_t)e * 3 + 1];
  const float w2 = ew[(size_t)e * 3 + 2];
  const float d = sqrtf(w0 * w0 + w1 * w1 + w2 * w2);
  const float invd = 1.f / d;
  float s1, c1;
  __sincosf(d * 0.628318530717958f, &s1, &c1);   // theta = pi*d/5
  const float env = (d < 5.f) ? 0.5f * (c1 + 1.f) : 0.f;

  uint4 r0, r1;
  r0.x = __float_as_uint(s1 * env * invd);
  r0.y = __float_as_uint(2.f * c1);
  r0.z = __float_as_uint(env);
  r0.w = __float_as_uint(w0 * invd);
  r1.x = __float_as_uint(w1 * invd);
  r1.y = __float_as_uint(w2 * invd);
  r1.z = (uint)j;
  r1.w = 0u;
  basisS[(size_t)pos * 2 + 0] = r0;
  basisS[(size_t)pos * 2 + 1] = r1;
}

// ---------------------------------------------------------------------------
// Phase 1: x = silu(q@W1+b1)@W2+b2; pack per (atom,feature t):
//   xmpA[n*128+t]  = x0|x1           (u32, read by gather groups 0 and 1)
//   xmpB[n*128+t]  = {x2|m0, m1|m2}  (u32x2, read by gather group 2)
// ---------------------------------------------------------------------------
__global__ __launch_bounds__(128) void mlp_kernel(
    const float* __restrict__ q, const float* __restrict__ mu,
    const float* __restrict__ W1, const float* __restrict__ b1,
    const float* __restrict__ W2, const float* __restrict__ b2v,
    uint* __restrict__ xmpA, uint2* __restrict__ xmpB)
{
  __shared__ float qL[MAPB][FD];
  __shared__ float hL[MAPB][FD];
  const int t = threadIdx.x;
  const int a0 = blockIdx.x * MAPB;

  #pragma unroll
  for (int a = 0; a < MAPB; ++a) qL[a][t] = q[(size_t)(a0 + a) * FD + t];
  __syncthreads();

  float hacc[MAPB];
  const float bb1 = b1[t];
  #pragma unroll
  for (int a = 0; a < MAPB; ++a) hacc[a] = bb1;
  for (int i = 0; i < FD; ++i) {
    const float w = W1[(size_t)i * FD + t];
    #pragma unroll
    for (int a = 0; a < MAPB; ++a) hacc[a] += qL[a][i] * w;
  }
  #pragma unroll
  for (int a = 0; a < MAPB; ++a) hL[a][t] = hacc[a] / (1.f + __expf(-hacc[a]));
  __syncthreads();

  float x0[MAPB], x1[MAPB], x2[MAPB];
  const float c0 = b2v[t], c1 = b2v[FD + t], c2 = b2v[2 * FD + t];
  #pragma unroll
  for (int a = 0; a < MAPB; ++a) { x0[a] = c0; x1[a] = c1; x2[a] = c2; }
  for (int i = 0; i < FD; ++i) {
    const float w0 = W2[(size_t)i * F3 + t];
    const float w1 = W2[(size_t)i * F3 + FD + t];
    const float w2 = W2[(size_t)i * F3 + 2 * FD + t];
    #pragma unroll
    for (int a = 0; a < MAPB; ++a) {
      const float hv = hL[a][i];
      x0[a] += hv * w0; x1[a] += hv * w1; x2[a] += hv * w2;
    }
  }
  #pragma unroll
  for (int a = 0; a < MAPB; ++a) {
    const int n = a0 + a;
    const float* ma = mu + (size_t)n * F3;
    const float m0 = ma[t], m1 = ma[FD + t], m2 = ma[2 * FD + t];
    xmpA[(size_t)n * FD + t] = f2bfu(x0[a]) | (f2bfu(x1[a]) << 16);
    uint2 vb;
    vb.x = f2bfu(x2[a]) | (f2bfu(m0) << 16);
    vb.y = f2bfu(m1)    | (f2bfu(m2) << 16);
    xmpB[(size_t)n * FD + t] = vb;
  }
}

// ---------------------------------------------------------------------------
// Phase 2: 384-thread blocks, GAPB=2 atoms each (contiguous CSR range).
// ONE filter column per thread (col = t): Wf slice is only 10 v2f = 20 VGPRs,
// so everything stays register-resident (the 128x3 layout needed 60 and the
// compiler rematerialized Wf loads inside the edge loop -> ~340us).
//   grp0 (t<128):    f*x0 -> q update
//   grp1 (128..255): f*x1 * dir -> mu partial (via LDS at flush)
//   grp2 (256..383): f*x2 * muj -> mu partial + final mu write
// Basis is Chebyshev-expanded once per 64-edge chunk into LDS; read back as
// 5x ds_read_b128 broadcasts. Depth-2 register pipeline on the gather load.
// ---------------------------------------------------------------------------
__global__ __launch_bounds__(384, 6) void gather_kernel(
    const float* __restrict__ q, const float* __restrict__ mu,
    const uint* __restrict__ xmpA, const uint2* __restrict__ xmpB,
    const float* __restrict__ Wf, const float* __restrict__ bfv,
    const int* __restrict__ off, const uint* __restrict__ basisS,
    float* __restrict__ out)
{
  __shared__ uint stage[64 * 8];   // raw 32B records
  __shared__ float fb[64][28];     // [0..19] basis f32, [20..23] env+dir, [24] j
  __shared__ float mured[3][128];  // grp1 -> grp2 partial handoff at flush
  const int t  = threadIdx.x;
  const int tc = t & 127;
  const int grp = t >> 7;          // wave-uniform (128 = 2 waves per group)
  const int a0 = blockIdx.x * GAPB;

  v2f wf[10];
  #pragma unroll
  for (int r = 0; r < 10; ++r)
    wf[r] = (v2f){Wf[(size_t)(2 * r) * F3 + t], Wf[(size_t)(2 * r + 1) * F3 + t]};
  const float bias = bfv[t];

  int a = a0;
  const int beg  = off[a0];
  const int pEnd = off[a0 + GAPB];
  int nxt = off[a + 1];
  float acq = 0.f, ac0 = 0.f, ac1 = 0.f, ac2 = 0.f;
  const size_t NQ = (size_t)NATOMS * FD;

  for (int base = beg; base < pEnd; base += 64) {
    const int nn = min(64, pEnd - base);
    __syncthreads();
    if (t < nn * 2) ((uint4*)stage)[t] = ((const uint4*)basisS)[(size_t)base * 2 + t];
    __syncthreads();
    if (t < nn) {
      const uint4 r0 = ((const uint4*)stage)[t * 2];
      const uint4 r1 = ((const uint4*)stage)[t * 2 + 1];
      fb[t][20] = __uint_as_float(r0.z);
      fb[t][21] = __uint_as_float(r0.w);
      fb[t][22] = __uint_as_float(r1.x);
      fb[t][23] = __uint_as_float(r1.y);
      fb[t][24] = __uint_as_float(r1.z);           // j bits
      float vp = 0.f, vc = __uint_as_float(r0.x);
      const float tcb = __uint_as_float(r0.y);
      #pragma unroll
      for (int r = 0; r < NR; ++r) { fb[t][r] = vc; const float vn = tcb * vc - vp; vp = vc; vc = vn; }
    }
    __syncthreads();

    // depth-2 pipeline, named scalars (no runtime-indexed arrays -> no scratch)
    uint pA = 0u, pB0 = 0u, pB1 = 0u;
    {
      const uint j0 = __float_as_uint(fb[0][24]);
      const size_t ad = (size_t)j0 * FD + tc;
      if (grp < 2) pA = xmpA[ad];
      else { const uint2 v = xmpB[ad]; pB0 = v.x; pB1 = v.y; }
    }

    for (int k = 0; k < nn; ++k) {
      const int g = base + k;
      while (g == nxt) {                           // block-uniform flush
        __syncthreads();
        if (grp == 1) { mured[0][tc] = ac0; mured[1][tc] = ac1; mured[2][tc] = ac2; }
        __syncthreads();
        if (grp == 0) out[(size_t)a * FD + tc] = q[(size_t)a * FD + tc] + acq;
        if (grp == 2) {
          const size_t mi = (size_t)a * F3;
          out[NQ + mi + tc]       = mu[mi + tc]       + ac0 + mured[0][tc];
          out[NQ + mi + 128 + tc] = mu[mi + 128 + tc] + ac1 + mured[1][tc];
          out[NQ + mi + 256 + tc] = mu[mi + 256 + tc] + ac2 + mured[2][tc];
        }
        acq = ac0 = ac1 = ac2 = 0.f;
        ++a;
        nxt = (a < NATOMS) ? off[a + 1] : 0x7fffffff;
      }

      uint nA = 0u, nB0 = 0u, nB1 = 0u;            // prefetch edge k+1
      if (k + 1 < nn) {
        const uint jj = __float_as_uint(fb[k + 1][24]);
        const size_t ad = (size_t)jj * FD + tc;
        if (grp < 2) nA = xmpA[ad];
        else { const uint2 v = xmpB[ad]; nB0 = v.x; nB1 = v.y; }
      }

      const float* fk = fb[k];
      const float4 M = *(const float4*)(fk + 20);  // env, dir0..2 (b128 broadcast)
      v2f s = (v2f){0.f, 0.f};
      #pragma unroll
      for (int r4 = 0; r4 < 5; ++r4) {             // 5x ds_read_b128 broadcast
        const float4 bv = ((const float4*)fk)[r4];
        s += (v2f){bv.x, bv.y} * wf[2 * r4];
        s += (v2f){bv.z, bv.w} * wf[2 * r4 + 1];
      }
      const float f = s.x + s.y + M.x * bias;

      if (grp == 0) {
        acq += f * bflo(pA);
      } else if (grp == 1) {
        const float dmuR = f * bfhi(pA);
        ac0 += dmuR * M.y; ac1 += dmuR * M.z; ac2 += dmuR * M.w;
      } else {
        const float dmm = f * bflo(pB0);
        ac0 += dmm * bfhi(pB0); ac1 += dmm * bflo(pB1); ac2 += dmm * bfhi(pB1);
      }
      pA = nA; pB0 = nB0; pB1 = nB1;
    }
  }

  while (a < a0 + GAPB) {                          // tail / zero-edge atoms
    __syncthreads();
    if (grp == 1) { mured[0][tc] = ac0; mured[1][tc] = ac1; mured[2][tc] = ac2; }
    __syncthreads();
    if (grp == 0) out[(size_t)a * FD + tc] = q[(size_t)a * FD + tc] + acq;
    if (grp == 2) {
      const size_t mi = (size_t)a * F3;
      out[NQ + mi + tc]       = mu[mi + tc]       + ac0 + mured[0][tc];
      out[NQ + mi + 128 + tc] = mu[mi + 128 + tc] + ac1 + mured[1][tc];
      out[NQ + mi + 256 + tc] = mu[mi + 256 + tc] + ac2 + mured[2][tc];
    }
    acq = ac0 = ac1 = ac2 = 0.f;
    ++a;
  }
}

extern "C" void kernel_launch(void* const* d_in, const int* in_sizes, int n_in,
                              void* d_out, int out_size, void* d_ws, size_t ws_size,
                              hipStream_t stream) {
  const float* q   = (const float*)d_in[0];
  const float* mu  = (const float*)d_in[1];
  const int*   eix = (const int*)d_in[2];
  const float* ew  = (const float*)d_in[3];
  const float* W1  = (const float*)d_in[4];
  const float* b1  = (const float*)d_in[5];
  const float* W2  = (const float*)d_in[6];
  const float* b2v = (const float*)d_in[7];
  const float* Wf  = (const float*)d_in[8];
  const float* bfv = (const float*)d_in[9];
  float* out = (float*)d_out;

  // Workspace (~51.4 MB): [basisS 32B*E | xmpA 4B*N*128 | xmpB 8B*N*128 | off | cnt | cursor]
  char* w = (char*)d_ws;
  uint*  basisS = (uint*)w;  w += (size_t)NEDGES * 32;
  uint*  xmpA   = (uint*)w;  w += (size_t)NATOMS * FD * sizeof(uint);
  uint2* xmpB   = (uint2*)w; w += (size_t)NATOMS * FD * sizeof(uint2);
  int*   off    = (int*)w;   w += (size_t)(NATOMS + 1) * sizeof(int);
  int*   cnt    = (int*)w;   w += (size_t)NATOMS * sizeof(int);
  int*   cursor = (int*)w;

  hipMemsetAsync(cnt, 0, (size_t)NATOMS * sizeof(int), stream);

  hist_kernel<<<(NEDGES + 255) / 256, 256, 0, stream>>>(eix, cnt);
  scan_kernel<<<1, 512, 0, stream>>>(cnt, off, cursor);
  prep_kernel<<<(NEDGES + 255) / 256, 256, 0, stream>>>(eix, ew, cursor,
                                                        (uint4*)basisS);

  mlp_kernel<<<NATOMS / MAPB, 128, 0, stream>>>(q, mu, W1, b1, W2, b2v,
                                                xmpA, xmpB);

  gather_kernel<<<NATOMS / GAPB, 384, 0, stream>>>(q, mu, xmpA, xmpB, Wf, bfv,
                                                   off, basisS, out);
}

// Round 2
// 480.717 us; speedup vs baseline: 1.5463x; 1.5463x over previous
//
#include <hip/hip_runtime.h>
#include <hip/hip_bf16.h>

typedef unsigned int uint;
typedef unsigned short ushort;
typedef float v2f __attribute__((ext_vector_type(2)));

#define NATOMS 20000
#define NEDGES 640000
#define FD 128
#define F3 384
#define NR 20
#define MAPB 16     // atoms per block, MLP
#define GAPB 2      // atoms per block, gather

__device__ __forceinline__ uint f2bfu(float f) {   // f32 -> bf16 bits, RNE
  const uint u = __float_as_uint(f);
  return (u + 0x7FFFu + ((u >> 16) & 1u)) >> 16;
}
__device__ __forceinline__ float bflo(uint u) { return __uint_as_float(u << 16); }
__device__ __forceinline__ float bfhi(uint u) { return __uint_as_float(u & 0xFFFF0000u); }

// ---------------------------------------------------------------------------
// CSR build: histogram -> exclusive scan (writes off AND cursor).
// ---------------------------------------------------------------------------
__global__ __launch_bounds__(256) void hist_kernel(const int* __restrict__ eidx,
                                                   int* __restrict__ cnt) {
  const int e = blockIdx.x * 256 + threadIdx.x;
  if (e < NEDGES) atomicAdd(&cnt[eidx[e]], 1);
}

__global__ __launch_bounds__(512) void scan_kernel(const int* __restrict__ cnt,
                                                   int* __restrict__ off,
                                                   int* __restrict__ cursor) {
  __shared__ int part[512];
  const int t = threadIdx.x;
  const int CH = (NATOMS + 511) / 512;
  const int base = t * CH;
  int s = 0;
  for (int k = 0; k < CH; ++k) {
    const int idx = base + k;
    if (idx < NATOMS) s += cnt[idx];
  }
  part[t] = s;
  __syncthreads();
  if (t == 0) {
    int run = 0;
    for (int i = 0; i < 512; ++i) { const int tmp = part[i]; part[i] = run; run += tmp; }
    off[NATOMS] = run;
  }
  __syncthreads();
  int run = part[t];
  for (int k = 0; k < CH; ++k) {
    const int idx = base + k;
    if (idx < NATOMS) { off[idx] = run; cursor[idx] = run; run += cnt[idx]; }
  }
}

// ---------------------------------------------------------------------------
// Prep: 32B record at destination-sorted position.
// rec: [0] v0=sin(th)*env/d  [1] 2cos(th)  [2] env  [3..5] dir  [6] j  [7] pad
// ---------------------------------------------------------------------------
__global__ __launch_bounds__(256) void prep_kernel(
    const int* __restrict__ eidx, const float* __restrict__ ew,
    int* __restrict__ cursor, uint4* __restrict__ basisS)
{
  const int e = blockIdx.x * 256 + threadIdx.x;
  if (e >= NEDGES) return;
  const int i = eidx[e];
  const int j = eidx[NEDGES + e];
  const int pos = atomicAdd(&cursor[i], 1);

  const float w0 = ew[(size_t)e * 3 + 0];
  const float w1 = ew[(size_t)e * 3 + 1];
  const float w2 = ew[(size_t)e * 3 + 2];
  const float d = sqrtf(w0 * w0 + w1 * w1 + w2 * w2);
  const float invd = 1.f / d;
  float s1, c1;
  __sincosf(d * 0.628318530717958f, &s1, &c1);   // theta = pi*d/5
  const float env = (d < 5.f) ? 0.5f * (c1 + 1.f) : 0.f;

  uint4 r0, r1;
  r0.x = __float_as_uint(s1 * env * invd);
  r0.y = __float_as_uint(2.f * c1);
  r0.z = __float_as_uint(env);
  r0.w = __float_as_uint(w0 * invd);
  r1.x = __float_as_uint(w1 * invd);
  r1.y = __float_as_uint(w2 * invd);
  r1.z = (uint)j;
  r1.w = 0u;
  basisS[(size_t)pos * 2 + 0] = r0;
  basisS[(size_t)pos * 2 + 1] = r1;
}

// ---------------------------------------------------------------------------
// Phase 1: x = silu(q@W1+b1)@W2+b2; pack per (atom,feature t) a 12B record
// [x0|x1, x2|m0, m1|m2] (bf16 pairs) -> gather reads ONE dwordx3 per edge.
// ---------------------------------------------------------------------------
__global__ __launch_bounds__(128) void mlp_kernel(
    const float* __restrict__ q, const float* __restrict__ mu,
    const float* __restrict__ W1, const float* __restrict__ b1,
    const float* __restrict__ W2, const float* __restrict__ b2v,
    uint* __restrict__ xmp)
{
  __shared__ float qL[MAPB][FD];
  __shared__ float hL[MAPB][FD];
  const int t = threadIdx.x;
  const int a0 = blockIdx.x * MAPB;

  #pragma unroll
  for (int a = 0; a < MAPB; ++a) qL[a][t] = q[(size_t)(a0 + a) * FD + t];
  __syncthreads();

  float hacc[MAPB];
  const float bb1 = b1[t];
  #pragma unroll
  for (int a = 0; a < MAPB; ++a) hacc[a] = bb1;
  for (int i = 0; i < FD; ++i) {
    const float w = W1[(size_t)i * FD + t];
    #pragma unroll
    for (int a = 0; a < MAPB; ++a) hacc[a] += qL[a][i] * w;
  }
  #pragma unroll
  for (int a = 0; a < MAPB; ++a) hL[a][t] = hacc[a] / (1.f + __expf(-hacc[a]));
  __syncthreads();

  float x0[MAPB], x1[MAPB], x2[MAPB];
  const float c0 = b2v[t], c1 = b2v[FD + t], c2 = b2v[2 * FD + t];
  #pragma unroll
  for (int a = 0; a < MAPB; ++a) { x0[a] = c0; x1[a] = c1; x2[a] = c2; }
  for (int i = 0; i < FD; ++i) {
    const float w0 = W2[(size_t)i * F3 + t];
    const float w1 = W2[(size_t)i * F3 + FD + t];
    const float w2 = W2[(size_t)i * F3 + 2 * FD + t];
    #pragma unroll
    for (int a = 0; a < MAPB; ++a) {
      const float hv = hL[a][i];
      x0[a] += hv * w0; x1[a] += hv * w1; x2[a] += hv * w2;
    }
  }
  #pragma unroll
  for (int a = 0; a < MAPB; ++a) {
    const int n = a0 + a;
    const float* ma = mu + (size_t)n * F3;
    const float m0 = ma[t], m1 = ma[FD + t], m2 = ma[2 * FD + t];
    uint* dst = xmp + ((size_t)n * FD + t) * 3;
    dst[0] = f2bfu(x0[a]) | (f2bfu(x1[a]) << 16);
    dst[1] = f2bfu(x2[a]) | (f2bfu(m0) << 16);
    dst[2] = f2bfu(m1)    | (f2bfu(m2) << 16);
  }
}

// ---------------------------------------------------------------------------
// Phase 2: 128-thread blocks, GAPB=2 atoms each (contiguous CSR range).
// Thread t owns filter columns {t, 128+t, 256+t} -> the 6 b128 basis
// broadcasts per edge are amortized over all 3 columns (the 1-col/384-thread
// variant tripled LDS issue and was LDS-bound at 494us).
// __launch_bounds__(128,3): VGPR cap ~170 so the 60-VGPR Wf slice stays
// register-resident (default cap of 68 forced AGPR/scratch shuffles, 340us).
// Depth-2 prefetch with NAMED scalars (runtime-indexed arrays -> scratch).
// ---------------------------------------------------------------------------
__global__ __launch_bounds__(128, 3) void gather_kernel(
    const float* __restrict__ q, const float* __restrict__ mu,
    const uint* __restrict__ xmp,
    const float* __restrict__ Wf, const float* __restrict__ bfv,
    const int* __restrict__ off, const uint* __restrict__ basisS,
    float* __restrict__ out)
{
  __shared__ uint stage[64 * 8];   // raw 32B records
  __shared__ float fb[64][28];     // [0..19] basis f32, [20..23] env+dir, [24] j
  const int t = threadIdx.x;
  const int a0 = blockIdx.x * GAPB;

  v2f wf0[10], wf1[10], wf2[10];
  #pragma unroll
  for (int r = 0; r < 10; ++r) {
    wf0[r] = (v2f){Wf[(size_t)(2 * r) * F3 + t],       Wf[(size_t)(2 * r + 1) * F3 + t]};
    wf1[r] = (v2f){Wf[(size_t)(2 * r) * F3 + 128 + t], Wf[(size_t)(2 * r + 1) * F3 + 128 + t]};
    wf2[r] = (v2f){Wf[(size_t)(2 * r) * F3 + 256 + t], Wf[(size_t)(2 * r + 1) * F3 + 256 + t]};
  }
  const float bias0 = bfv[t], bias1 = bfv[128 + t], bias2 = bfv[256 + t];

  int a = a0;
  const int beg  = off[a0];
  const int pEnd = off[a0 + GAPB];
  int nxt = off[a + 1];
  float acq = 0.f, ac0 = 0.f, ac1 = 0.f, ac2 = 0.f;
  const size_t NQ = (size_t)NATOMS * FD;

  for (int cb = beg; cb < pEnd; cb += 64) {
    const int nn = min(64, pEnd - cb);
    __syncthreads();
    if (t < nn * 2) ((uint4*)stage)[t] = ((const uint4*)basisS)[(size_t)cb * 2 + t];
    __syncthreads();
    if (t < nn) {
      const uint4 r0 = ((const uint4*)stage)[t * 2];
      const uint4 r1 = ((const uint4*)stage)[t * 2 + 1];
      fb[t][20] = __uint_as_float(r0.z);
      fb[t][21] = __uint_as_float(r0.w);
      fb[t][22] = __uint_as_float(r1.x);
      fb[t][23] = __uint_as_float(r1.y);
      fb[t][24] = __uint_as_float(r1.z);           // j bits
      float vp = 0.f, vc = __uint_as_float(r0.x);
      const float tc = __uint_as_float(r0.y);
      #pragma unroll
      for (int r = 0; r < NR; ++r) { fb[t][r] = vc; const float vn = tc * vc - vp; vp = vc; vc = vn; }
    }
    __syncthreads();

    // depth-2 pipeline on the 12B gather, named scalar registers
    uint pX, pY, pZ;
    {
      const uint j0 = __float_as_uint(fb[0][24]);
      const uint* xp = xmp + ((size_t)j0 * FD + t) * 3;
      pX = xp[0]; pY = xp[1]; pZ = xp[2];
    }

    for (int k = 0; k < nn; ++k) {
      const int g = cb + k;
      while (g == nxt) {                           // block-uniform flush
        out[(size_t)a * FD + t] = q[(size_t)a * FD + t] + acq;
        const size_t mi = (size_t)a * F3;
        out[NQ + mi + t]       = mu[mi + t]       + ac0;
        out[NQ + mi + 128 + t] = mu[mi + 128 + t] + ac1;
        out[NQ + mi + 256 + t] = mu[mi + 256 + t] + ac2;
        acq = ac0 = ac1 = ac2 = 0.f;
        ++a;
        nxt = (a < NATOMS) ? off[a + 1] : 0x7fffffff;
      }

      uint nX = 0u, nY = 0u, nZ = 0u;              // prefetch edge k+1
      if (k + 1 < nn) {
        const uint jj = __float_as_uint(fb[k + 1][24]);
        const uint* xp = xmp + ((size_t)jj * FD + t) * 3;
        nX = xp[0]; nY = xp[1]; nZ = xp[2];
      }

      const float* fk = fb[k];
      const float4 M = *(const float4*)(fk + 20);  // env, dir0..2 (b128 broadcast)
      v2f s0 = (v2f){0.f, 0.f}, s1 = (v2f){0.f, 0.f}, s2 = (v2f){0.f, 0.f};
      #pragma unroll
      for (int r4 = 0; r4 < 5; ++r4) {             // 5x ds_read_b128 broadcast
        const float4 bv = ((const float4*)fk)[r4];
        const v2f blo = (v2f){bv.x, bv.y};
        const v2f bhi = (v2f){bv.z, bv.w};
        s0 += blo * wf0[2 * r4]; s0 += bhi * wf0[2 * r4 + 1];
        s1 += blo * wf1[2 * r4]; s1 += bhi * wf1[2 * r4 + 1];
        s2 += blo * wf2[2 * r4]; s2 += bhi * wf2[2 * r4 + 1];
      }
      const float env = M.x;
      const float f0 = s0.x + s0.y + env * bias0;
      const float f1 = s1.x + s1.y + env * bias1;
      const float f2 = s2.x + s2.y + env * bias2;

      acq += f0 * bflo(pX);
      const float dmuR = f1 * bfhi(pX);
      const float dmm  = f2 * bflo(pY);
      ac0 += dmuR * M.y + dmm * bfhi(pY);
      ac1 += dmuR * M.z + dmm * bflo(pZ);
      ac2 += dmuR * M.w + dmm * bfhi(pZ);

      pX = nX; pY = nY; pZ = nZ;
    }
  }
  while (a < a0 + GAPB) {                          // tail / zero-edge atoms
    out[(size_t)a * FD + t] = q[(size_t)a * FD + t] + acq;
    const size_t mi = (size_t)a * F3;
    out[NQ + mi + t]       = mu[mi + t]       + ac0;
    out[NQ + mi + 128 + t] = mu[mi + 128 + t] + ac1;
    out[NQ + mi + 256 + t] = mu[mi + 256 + t] + ac2;
    acq = ac0 = ac1 = ac2 = 0.f;
    ++a;
  }
}

extern "C" void kernel_launch(void* const* d_in, const int* in_sizes, int n_in,
                              void* d_out, int out_size, void* d_ws, size_t ws_size,
                              hipStream_t stream) {
  const float* q   = (const float*)d_in[0];
  const float* mu  = (const float*)d_in[1];
  const int*   eix = (const int*)d_in[2];
  const float* ew  = (const float*)d_in[3];
  const float* W1  = (const float*)d_in[4];
  const float* b1  = (const float*)d_in[5];
  const float* W2  = (const float*)d_in[6];
  const float* b2v = (const float*)d_in[7];
  const float* Wf  = (const float*)d_in[8];
  const float* bfv = (const float*)d_in[9];
  float* out = (float*)d_out;

  // Workspace (~51.4 MB): [basisS 32B*E | xmp 12B*N*128 | off N+1 | cnt N | cursor N]
  char* w = (char*)d_ws;
  uint* basisS = (uint*)w;  w += (size_t)NEDGES * 32;
  uint* xmp    = (uint*)w;  w += (size_t)NATOMS * FD * 3 * sizeof(uint);
  int*  off    = (int*)w;   w += (size_t)(NATOMS + 1) * sizeof(int);
  int*  cnt    = (int*)w;   w += (size_t)NATOMS * sizeof(int);
  int*  cursor = (int*)w;

  hipMemsetAsync(cnt, 0, (size_t)NATOMS * sizeof(int), stream);

  hist_kernel<<<(NEDGES + 255) / 256, 256, 0, stream>>>(eix, cnt);
  scan_kernel<<<1, 512, 0, stream>>>(cnt, off, cursor);
  prep_kernel<<<(NEDGES + 255) / 256, 256, 0, stream>>>(eix, ew, cursor,
                                                        (uint4*)basisS);

  mlp_kernel<<<NATOMS / MAPB, 128, 0, stream>>>(q, mu, W1, b1, W2, b2v, xmp);

  gather_kernel<<<NATOMS / GAPB, 128, 0, stream>>>(q, mu, xmp, Wf, bfv,
                                                   off, basisS, out);
}